// Round 1
// baseline (339.075 us; speedup 1.0000x reference)
//
#include <hip/hip_runtime.h>

// ---- constants for this problem ----
// x: (81920, 256) f32 ; W_qkv: (256, 768) f32 ; W_proj: (256,256) f32 ; b_proj: (256,) f32
// B=4 batches, L=20480 rows/batch, H=8 heads, d=32, out: (81920,256) f32
#define M_ROWS 81920
#define KDIM 256
#define NQKV 768
#define LROWS 20480
#define EPSV 1e-6f

using bf16x8 = __attribute__((ext_vector_type(8))) short;
using f32x4  = __attribute__((ext_vector_type(4))) float;

static __device__ __forceinline__ unsigned short f2bf(float f) {
  union { float f; unsigned int u; } c; c.f = f;
  unsigned int u = c.u;
  u += 0x7fff + ((u >> 16) & 1);   // round-to-nearest-even
  return (unsigned short)(u >> 16);
}
static __device__ __forceinline__ float bf2f(unsigned short h) {
  union { unsigned int u; float f; } c; c.u = ((unsigned int)h) << 16;
  return c.f;
}

// async global->LDS 16B copy (wave-uniform base + lane*16 LDS pattern required)
static __device__ __forceinline__ void async_cp16(const void* g, void* l) {
  __builtin_amdgcn_global_load_lds(
      (const __attribute__((address_space(1))) void*)(unsigned long long)g,
      (__attribute__((address_space(3))) void*)(unsigned int)(unsigned long long)l,
      16, 0, 0);
}

// ---------------- convert / transpose ----------------
__global__ void cvt_x(const float* __restrict__ x, unsigned short* __restrict__ xb) {
  long i = ((long)blockIdx.x * blockDim.x + threadIdx.x) * 4;
  float4 v = *(const float4*)(x + i);
  ushort4 o;
  o.x = f2bf(v.x); o.y = f2bf(v.y); o.z = f2bf(v.z); o.w = f2bf(v.w);
  *(ushort4*)(xb + i) = o;
}

__global__ void transpose_w(const float* __restrict__ w, unsigned short* __restrict__ wt,
                            int K, int N) {
  // w: K x N  ->  wt: N x K (bf16)
  int k = blockIdx.x;
  for (int n = threadIdx.x; n < N; n += blockDim.x)
    wt[(size_t)n * K + k] = f2bf(w[(size_t)k * N + n]);
}

// ---------------- bf16 MFMA GEMM, C = A @ Bt^T ----------------
// A: M x 256 bf16 row-major. Bt: N x 256 bf16 row-major.
// EPI==0: N=768, elu+1 on cols<512, store bf16 (qkv buffer)
// EPI==1: N=256, Bt batched per 20480 rows (Gt + nb*256*256), add bias, store f32
template <int EPI>
__global__ __launch_bounds__(256, 3)
void gemm_bt(const unsigned short* __restrict__ A,
             const unsigned short* __restrict__ Bt,
             void* __restrict__ C,
             const float* __restrict__ bias,
             int N) {
  __shared__ unsigned short As[128 * 32];
  __shared__ unsigned short Bs[128 * 32];
  const int K = 256;
  int t = threadIdx.x;
  int lane = t & 63;
  int w = t >> 6;
  int m0 = blockIdx.y * 128;
  int n0 = blockIdx.x * 128;
  const unsigned short* Bp = Bt;
  if (EPI == 1) Bp += (size_t)(blockIdx.y / 160) * 256 * 256;

  f32x4 acc[4][4];
#pragma unroll
  for (int i = 0; i < 4; i++)
#pragma unroll
    for (int j = 0; j < 4; j++) acc[i][j] = (f32x4){0.f, 0.f, 0.f, 0.f};

  int wm = w & 1, wn = w >> 1;
  int fm = lane & 15;
  int fk = (lane >> 4) * 8;
  int r0a = t >> 2, p0 = t & 3;          // chunk t
  int r1a = (t + 256) >> 2, p1 = t & 3;  // chunk t+256 (same low bits)

  for (int kt = 0; kt < 8; kt++) {
    int k0 = kt * 32;
    __syncthreads();
    async_cp16(A + (size_t)(m0 + r0a) * K + k0 + p0 * 8, As + (size_t)t * 8);
    async_cp16(A + (size_t)(m0 + r1a) * K + k0 + p1 * 8, As + (size_t)(t + 256) * 8);
    async_cp16(Bp + (size_t)(n0 + r0a) * K + k0 + p0 * 8, Bs + (size_t)t * 8);
    async_cp16(Bp + (size_t)(n0 + r1a) * K + k0 + p1 * 8, Bs + (size_t)(t + 256) * 8);
    __syncthreads();
    bf16x8 af[4], bfr[4];
#pragma unroll
    for (int i = 0; i < 4; i++)
      af[i] = *(const bf16x8*)(As + (wm * 64 + i * 16 + fm) * 32 + fk);
#pragma unroll
    for (int j = 0; j < 4; j++)
      bfr[j] = *(const bf16x8*)(Bs + (wn * 64 + j * 16 + fm) * 32 + fk);
#pragma unroll
    for (int i = 0; i < 4; i++)
#pragma unroll
      for (int j = 0; j < 4; j++)
        acc[i][j] = __builtin_amdgcn_mfma_f32_16x16x32_bf16(af[i], bfr[j], acc[i][j], 0, 0, 0);
  }

  int quad = lane >> 4;
  int col = lane & 15;
#pragma unroll
  for (int i = 0; i < 4; i++) {
#pragma unroll
    for (int j = 0; j < 4; j++) {
      int gm_base = m0 + wm * 64 + i * 16 + quad * 4;
      int gn = n0 + wn * 64 + j * 16 + col;
#pragma unroll
      for (int r = 0; r < 4; r++) {
        float v = acc[i][j][r];
        int gm = gm_base + r;
        if (EPI == 0) {
          if (gn < 512) v = (v > 0.f) ? v + 1.f : __expf(v);  // elu(v)+1
          ((unsigned short*)C)[(size_t)gm * N + gn] = f2bf(v);
        } else {
          ((float*)C)[(size_t)gm * N + gn] = v + bias[gn];
        }
      }
    }
  }
}

// ---------------- kv & k_sum reduction ----------------
// kv[n,h,m,d] = sum_l k[n,l,h,d]*v[n,l,h,m] ; ksum[n,h,d] = sum_l k
// grid (32 pairs, 16 chunks), block 256. qkv bf16 (M x 768): k at col 256+h*32, v at 512+h*32
__global__ __launch_bounds__(256)
void kv_reduce(const unsigned short* __restrict__ qkv, float* __restrict__ kv,
               float* __restrict__ ksum) {
  __shared__ unsigned short s[64 * 64];  // per row: [k(32) | v(32)] bf16
  int pair = blockIdx.x;
  int n = pair >> 3, h = pair & 7;
  int chunk = blockIdx.y;
  const int RC = LROWS / 16;  // 1280 rows per chunk
  int r0 = n * LROWS + chunk * RC;
  int t = threadIdx.x;
  int lane = t & 63;
  int w = t >> 6;

  float accv[4][4] = {};
  float ks[4] = {};
  int mg = lane >> 3;
  int m0 = mg * 4, d0 = (lane & 7) * 4;

  // staging chunk mapping: chunk c -> row=c>>3, part=c&7 ; part<4: k, else v
  int row0 = t >> 3, part0 = t & 7;
  int row1 = (t + 256) >> 3, part1 = t & 7;

  for (int tile = 0; tile < RC / 64; tile++) {
    __syncthreads();
    {
      size_t gr = (size_t)(r0 + tile * 64 + row0) * 768;
      const unsigned short* g = (part0 < 4) ? (qkv + gr + 256 + h * 32 + part0 * 8)
                                            : (qkv + gr + 512 + h * 32 + (part0 - 4) * 8);
      async_cp16(g, s + (size_t)t * 8);
      gr = (size_t)(r0 + tile * 64 + row1) * 768;
      g = (part1 < 4) ? (qkv + gr + 256 + h * 32 + part1 * 8)
                      : (qkv + gr + 512 + h * 32 + (part1 - 4) * 8);
      async_cp16(g, s + (size_t)(t + 256) * 8);
    }
    __syncthreads();
    for (int rr = 0; rr < 16; rr++) {
      int row = w * 16 + rr;
      ushort4 kk = *(const ushort4*)(s + row * 64 + d0);
      ushort4 vv = *(const ushort4*)(s + row * 64 + 32 + m0);
      float kf[4] = {bf2f(kk.x), bf2f(kk.y), bf2f(kk.z), bf2f(kk.w)};
      float vf[4] = {bf2f(vv.x), bf2f(vv.y), bf2f(vv.z), bf2f(vv.w)};
#pragma unroll
      for (int i = 0; i < 4; i++)
#pragma unroll
        for (int j = 0; j < 4; j++) accv[i][j] += vf[i] * kf[j];
      if (mg == 0) {
        ks[0] += kf[0]; ks[1] += kf[1]; ks[2] += kf[2]; ks[3] += kf[3];
      }
    }
  }
  float* base = kv + (size_t)pair * 1024;
#pragma unroll
  for (int i = 0; i < 4; i++)
#pragma unroll
    for (int j = 0; j < 4; j++) atomicAdd(base + (m0 + i) * 32 + (d0 + j), accv[i][j]);
  if (mg == 0) {
    float* kb = ksum + pair * 32;
#pragma unroll
    for (int j = 0; j < 4; j++) atomicAdd(kb + d0 + j, ks[j]);
  }
}

// ---------------- fold kv into W_proj: Gt[n][c][h*32+d] = sum_m kv[n,h,m,d]*Wp[h*32+m][c]
__global__ __launch_bounds__(256)
void make_g(const float* __restrict__ kv, const float* __restrict__ wproj,
            unsigned short* __restrict__ gt) {
  __shared__ float kvs[1024];
  int pair = blockIdx.x;
  int n = pair >> 3, h = pair & 7;
  int c = threadIdx.x;
  for (int i = c; i < 1024; i += 256) kvs[i] = kv[(size_t)pair * 1024 + i];
  __syncthreads();
  float acc[32];
#pragma unroll
  for (int d = 0; d < 32; d++) acc[d] = 0.f;
  for (int m = 0; m < 32; m++) {
    float wp = wproj[(size_t)(h * 32 + m) * 256 + c];
#pragma unroll
    for (int d = 0; d < 32; d++) acc[d] += kvs[m * 32 + d] * wp;
  }
  unsigned short* o = gt + ((size_t)n * 256 + c) * 256 + h * 32;
#pragma unroll
  for (int d = 0; d < 32; d++) o[d] = f2bf(acc[d]);
}

// ---------------- per-row z and q' = z*q (bf16) ----------------
__global__ __launch_bounds__(256)
void scale_q(const unsigned short* __restrict__ qkv, const float* __restrict__ ksum,
             unsigned short* __restrict__ qp) {
  int t = threadIdx.x;
  int lane32 = t & 31;  // cols lane32*8 .. +7 (head = lane32/4)
  int rsub = t >> 5;    // 0..7
  long r0 = (long)blockIdx.x * 64;
  for (int p = 0; p < 8; p++) {
    long r = r0 + p * 8 + rsub;
    int n = (int)(r / LROWS);
    const unsigned short* q = qkv + r * 768 + lane32 * 8;
    ushort4 a = *(const ushort4*)(q);
    ushort4 b = *(const ushort4*)(q + 4);
    float qf[8] = {bf2f(a.x), bf2f(a.y), bf2f(a.z), bf2f(a.w),
                   bf2f(b.x), bf2f(b.y), bf2f(b.z), bf2f(b.w)};
    const float* ks = ksum + n * 256 + lane32 * 8;
    float sacc = 0.f;
#pragma unroll
    for (int i = 0; i < 8; i++) sacc += qf[i] * ks[i];
    sacc += __shfl_xor(sacc, 1);
    sacc += __shfl_xor(sacc, 2);
    float z = 1.f / (sacc + EPSV);
    ushort4 oa, ob;
    oa.x = f2bf(qf[0] * z); oa.y = f2bf(qf[1] * z);
    oa.z = f2bf(qf[2] * z); oa.w = f2bf(qf[3] * z);
    ob.x = f2bf(qf[4] * z); ob.y = f2bf(qf[5] * z);
    ob.z = f2bf(qf[6] * z); ob.w = f2bf(qf[7] * z);
    unsigned short* o = qp + r * 256 + lane32 * 8;
    *(ushort4*)o = oa;
    *(ushort4*)(o + 4) = ob;
  }
}

// ---------------- launch ----------------
extern "C" void kernel_launch(void* const* d_in, const int* in_sizes, int n_in,
                              void* d_out, int out_size, void* d_ws, size_t ws_size,
                              hipStream_t stream) {
  (void)in_sizes; (void)n_in; (void)out_size; (void)ws_size;
  const float* x = (const float*)d_in[0];
  const float* Wqkv = (const float*)d_in[1];
  const float* Wproj = (const float*)d_in[2];
  const float* bproj = (const float*)d_in[3];
  float* out = (float*)d_out;

  char* ws = (char*)d_ws;
  unsigned short* xbf    = (unsigned short*)(ws);                       // 81920*256*2
  unsigned short* wqkvt  = (unsigned short*)(ws + 41943040);            // 768*256*2
  unsigned short* qkv_bf = (unsigned short*)(ws + 42336256);            // 81920*768*2
  float*          kv     = (float*)(ws + 168165376);                    // 32768*4
  float*          ksum   = (float*)(ws + 168296448);                    // 1024*4
  unsigned short* gt     = (unsigned short*)(ws + 168300544);           // 4*256*256*2
  unsigned short* qp     = (unsigned short*)(ws + 168824832);           // 81920*256*2

  hipMemsetAsync(kv, 0, 131072 + 4096, stream);  // kv + ksum contiguous

  cvt_x<<<M_ROWS * KDIM / 1024, 256, 0, stream>>>(x, xbf);
  transpose_w<<<256, 256, 0, stream>>>(Wqkv, wqkvt, 256, 768);
  gemm_bt<0><<<dim3(NQKV / 128, M_ROWS / 128), 256, 0, stream>>>(xbf, wqkvt, qkv_bf, nullptr, NQKV);
  kv_reduce<<<dim3(32, 16), 256, 0, stream>>>(qkv_bf, kv, ksum);
  make_g<<<32, 256, 0, stream>>>(kv, Wproj, gt);
  scale_q<<<M_ROWS / 64, 256, 0, stream>>>(qkv_bf, ksum, qp);
  gemm_bt<1><<<dim3(2, M_ROWS / 128), 256, 0, stream>>>(qp, gt, out, bproj, 256);
}